// Round 7
// baseline (1073.880 us; speedup 1.0000x reference)
//
#include <hip/hip_runtime.h>

// VectorQuantizerEMA  N=32768 K=8192 D=256  fp32
// Outputs: z_q_st[N*D], commitment[1], idx[N], new_embed[K*D], new_count[K], new_avg[K*D]
//
// Pass 1: fp16 MFMA GEMM (z16 * (w*2^14)16), m97-shape 128x128 tile, BK=64,
//         ONE epilogue per block: score = cw - 2^-13*acc, wave-local row min
//         tightened via global rmin_map atomicMin-return, windowed inserts.
// Pass 2: compact (prune by final global min) -> exact fp32-chain dist
//         (bit-exact vs numpy/OpenBLAS) -> atomicMin (fmap(dist)<<32|n)
//         = numpy first-index tie-break.

typedef _Float16 half8 __attribute__((ext_vector_type(8)));
typedef _Float16 half4 __attribute__((ext_vector_type(4)));
typedef __attribute__((ext_vector_type(4))) float floatx4;

namespace {
constexpr int kN = 32768;
constexpr int kK = 8192;
constexpr int kD = 256;
constexpr int CAP = 64;
constexpr int FLATCAP = 1 << 21;
constexpr float WWIN = 2.0e-4f;  // containment needs ~8.5e-5; 2.3x margin

// ---- workspace layout (bytes) ----
constexpr size_t OFF_HIST = 0;                                // int K
constexpr size_t OFF_NS   = OFF_HIST + (size_t)kK * 4;        // double
constexpr size_t OFF_GCNT = OFF_NS + 8;                       // uint N
constexpr size_t OFF_CCNT = OFF_GCNT + (size_t)kN * 4;        // int
constexpr size_t ZERO_BYTES = OFF_CCNT + 8;
constexpr size_t OFF_RKEY = (ZERO_BYTES + 63) & ~(size_t)63;  // ull N   } one
constexpr size_t OFF_RMIN = OFF_RKEY + (size_t)kN * 8;        // uint N  } 0xFF memset
constexpr size_t FF_BYTES = (size_t)kN * 12;
constexpr size_t OFF_SZ   = OFF_RMIN + (size_t)kN * 4;        // float N
constexpr size_t OFF_CW   = OFF_SZ + (size_t)kN * 4;          // float K
constexpr size_t OFF_Z16  = OFF_CW + (size_t)kK * 4;          // f16 N*D
constexpr size_t OFF_W16  = OFF_Z16 + (size_t)kN * kD * 2;    // f16 K*D
constexpr size_t OFF_CAND = OFF_W16 + (size_t)kK * kD * 2;    // int2 N*CAP
constexpr size_t OFF_FLAT = OFF_CAND + (size_t)kN * CAP * 8;  // int2 FLATCAP
constexpr size_t OFF_IDX  = OFF_FLAT + (size_t)FLATCAP * 8;   // int N
constexpr size_t OFF_OFFS = OFF_IDX + (size_t)kN * 4;         // int K
constexpr size_t OFF_CUR  = OFF_OFFS + (size_t)kK * 4;        // int K
constexpr size_t OFF_ROWL = OFF_CUR + (size_t)kK * 4;         // int N
constexpr size_t OFF_PART = OFF_ROWL + (size_t)kN * 4;        // double N
} // namespace

__device__ __forceinline__ unsigned fmap(float f) {
  unsigned u = __float_as_uint(f);
  return (u & 0x80000000u) ? ~u : (u | 0x80000000u);
}
__device__ __forceinline__ float funmap(unsigned m) {
  unsigned u = (m & 0x80000000u) ? (m & 0x7fffffffu) : ~m;
  return __uint_as_float(u);
}
__device__ __forceinline__ void gload16(const void* g, void* l) {
  __builtin_amdgcn_global_load_lds(
      (const __attribute__((address_space(1))) unsigned int*)g,
      (__attribute__((address_space(3))) unsigned int*)l, 16, 0, 0);
}

// ---------------- numpy AVX512 pairwise sum of squares ----------------
__device__ __forceinline__ float pw_block128_sq(const float* __restrict__ p) {
#pragma clang fp contract(off)
  float u[16];
#pragma unroll
  for (int l = 0; l < 16; ++l) {
    const float x0 = p[l] * p[l];
    const float x1 = p[16 + l] * p[16 + l];
    const float x2 = p[32 + l] * p[32 + l];
    const float x3 = p[48 + l] * p[48 + l];
    const float x4 = p[64 + l] * p[64 + l];
    const float x5 = p[80 + l] * p[80 + l];
    const float x6 = p[96 + l] * p[96 + l];
    const float x7 = p[112 + l] * p[112 + l];
    u[l] = ((x0 + x1) + (x2 + x3)) + ((x4 + x5) + (x6 + x7));
  }
  float t1[8], t2[4], t3[2];
#pragma unroll
  for (int l = 0; l < 8; ++l) t1[l] = u[l] + u[l + 8];
#pragma unroll
  for (int l = 0; l < 4; ++l) t2[l] = t1[l] + t1[l + 4];
#pragma unroll
  for (int l = 0; l < 2; ++l) t3[l] = t2[l] + t2[l + 2];
  return t3[0] + t3[1];
}

// ---------------- fused fp16 convert + numpy-order row sums (z and w) ------
__global__ __launch_bounds__(256) void prep2(const float* __restrict__ z,
                                             const float* __restrict__ w,
                                             _Float16* __restrict__ z16,
                                             _Float16* __restrict__ w16,
                                             float* __restrict__ sz,
                                             float* __restrict__ cw) {
  const bool isz = (blockIdx.x < kN / 256);
  const int b = isz ? blockIdx.x : blockIdx.x - kN / 256;
  const int nblocks = isz ? kN / 256 : kK / 256;
  const int nrows = isz ? kN : kK;
  const float scale = isz ? 1.0f : 16384.0f;
  const float* x = isz ? z : w;
  _Float16* out16 = isz ? z16 : w16;
  float* sums = isz ? sz : cw;

  const int gid = b * 256 + threadIdx.x;
  const int gtot = nblocks * 256;
  const int nf4 = nrows * (kD / 4);
  for (int i = gid; i < nf4; i += gtot) {
    const float4 v = ((const float4*)x)[i];
    half4 h;
    h.x = (_Float16)(v.x * scale);
    h.y = (_Float16)(v.y * scale);
    h.z = (_Float16)(v.z * scale);
    h.w = (_Float16)(v.w * scale);
    ((half4*)out16)[i] = h;
  }
  for (int r = gid; r < nrows; r += gtot) {
    const float* p = x + (size_t)r * kD;
    sums[r] = pw_block128_sq(p) + pw_block128_sq(p + 128);
  }
}

// ---------------- MFMA filter pass: m97-shape 128x128, BK=64 ----------------
// grid 16384 = 256 mtiles x 64 ntiles (ntile inner for A-tile L2 reuse).
__global__ __launch_bounds__(256, 4) void score_kernel(
    const _Float16* __restrict__ z16, const _Float16* __restrict__ w16,
    const float* __restrict__ cw, unsigned* __restrict__ gcnt,
    int2* __restrict__ gcand, unsigned* __restrict__ rmin_map) {
  __shared__ _Float16 As[128 * 64];  // 16 KB, XOR-swizzled 16B chunks (8/row)
  __shared__ _Float16 Bs[128 * 64];  // 16 KB

  const int tid = threadIdx.x;
  const int wid = tid >> 6;
  const int lane = tid & 63;
  const int l16 = lane & 15;
  const int quad = lane >> 4;
  const int m0 = (blockIdx.x >> 6) * 128;
  const int n0 = (blockIdx.x & 63) * 128;
  const int rowbase = (wid >> 1) * 64;
  const int colbase = (wid & 1) * 64;

  floatx4 acc[4][4];
#pragma unroll
  for (int a = 0; a < 4; ++a)
#pragma unroll
    for (int b = 0; b < 4; ++b) acc[a][b] = (floatx4){0.f, 0.f, 0.f, 0.f};

  for (int kt = 0; kt < 4; ++kt) {
    const int d0 = kt * 64;
    __syncthreads();  // prior-iter LDS reads complete before overwrite
#pragma unroll
    for (int p = 0; p < 4; ++p) {  // A: 128 rows x 64 d
      const int q = p * 4 + wid;
      const int r = q * 8 + (lane >> 3);
      const int c = (lane & 7) ^ (r & 7);
      gload16(z16 + (size_t)(m0 + r) * kD + d0 + c * 8, &As[q * 512]);
    }
#pragma unroll
    for (int p = 0; p < 4; ++p) {  // B: 128 codes x 64 d
      const int q = p * 4 + wid;
      const int r = q * 8 + (lane >> 3);
      const int c = (lane & 7) ^ (r & 7);
      gload16(w16 + (size_t)(n0 + r) * kD + d0 + c * 8, &Bs[q * 512]);
    }
    __syncthreads();  // drain staging
#pragma unroll
    for (int kc = 0; kc < 2; ++kc) {
      half8 af[4], bfr[4];
#pragma unroll
      for (int mt = 0; mt < 4; ++mt) {
        const int row = rowbase + mt * 16 + l16;
        const int j = (kc * 4 + quad) ^ (row & 7);
        af[mt] = *(const half8*)&As[row * 64 + j * 8];
      }
#pragma unroll
      for (int nt = 0; nt < 4; ++nt) {
        const int row = colbase + nt * 16 + l16;
        const int j = (kc * 4 + quad) ^ (row & 7);
        bfr[nt] = *(const half8*)&Bs[row * 64 + j * 8];
      }
#pragma unroll
      for (int mt = 0; mt < 4; ++mt)
#pragma unroll
        for (int nt = 0; nt < 4; ++nt)
          acc[mt][nt] = __builtin_amdgcn_mfma_f32_16x16x32_f16(
              af[mt], bfr[nt], acc[mt][nt], 0, 0, 0);
    }
  }

  // ---- single epilogue: scores, wave-local row min + global tighten, inserts
  float cwv[4];
#pragma unroll
  for (int nt = 0; nt < 4; ++nt)
    cwv[nt] = cw[n0 + colbase + nt * 16 + l16];

#pragma unroll
  for (int mt = 0; mt < 4; ++mt) {
#pragma unroll
    for (int r = 0; r < 4; ++r) {
      float mn = 3.4e38f;
#pragma unroll
      for (int nt = 0; nt < 4; ++nt) {
        // w scaled by 2^14: -2*2^-14 = -2^-13 exactly
        const float s = fmaf(acc[mt][nt][r], -1.220703125e-4f, cwv[nt]);
        acc[mt][nt][r] = s;
        mn = fminf(mn, s);
      }
      // row-min across the 16 cols held by this quad-group (lane bits 0-3)
#pragma unroll
      for (int off = 1; off < 16; off <<= 1)
        mn = fminf(mn, __shfl_xor(mn, off));
      const int m = m0 + rowbase + mt * 16 + quad * 4 + r;
      unsigned old = 0xFFFFFFFFu;
      const unsigned key = fmap(mn);
      if (l16 == 0) old = atomicMin(&rmin_map[m], key);
      old = __shfl(old, quad << 4);  // broadcast from this quad's l16==0 lane
      const unsigned cur = old < key ? old : key;
      const float thr = funmap(cur) + WWIN;
#pragma unroll
      for (int nt = 0; nt < 4; ++nt) {
        const float s = acc[mt][nt][r];
        if (s <= thr) {
          const int n = n0 + colbase + nt * 16 + l16;
          const unsigned pos = atomicAdd(&gcnt[m], 1u);
          if (pos < CAP)
            gcand[(size_t)m * CAP + pos] = make_int2(__float_as_int(s), n);
        }
      }
    }
  }
}

// ---------------- compact candidates into flat list (wave per row) --------
__global__ __launch_bounds__(256) void compact_kernel(
    const unsigned* __restrict__ gcnt, const int2* __restrict__ gcand,
    const unsigned* __restrict__ rmin_map, int2* __restrict__ flat,
    int* __restrict__ ccnt) {
  const int wid = threadIdx.x >> 6;
  const int lane = threadIdx.x & 63;
  const int m = blockIdx.x * 4 + wid;
  const unsigned cnt = gcnt[m];
  if (cnt <= (unsigned)CAP) {
    const float thr = funmap(rmin_map[m]) + WWIN;  // final global min: tight
    int n = 0;
    bool keep = false;
    if (lane < (int)cnt) {
      const int2 cd = gcand[(size_t)m * CAP + lane];
      keep = (__int_as_float(cd.x) <= thr);
      n = cd.y;
    }
    const unsigned long long mask = __ballot(keep);
    const int tot = __popcll(mask);
    int base = 0;
    if (lane == 0 && tot) base = atomicAdd(ccnt, tot);
    base = __shfl(base, 0);
    if (keep && base + tot <= FLATCAP) {
      const int rank = __popcll(mask & ((1ull << lane) - 1ull));
      flat[base + rank] = make_int2(m, n);
    }
  } else {
    // overflow (rare): emit all K codes for exact scan
    int base = 0;
    if (lane == 0) base = atomicAdd(ccnt, kK);
    base = __shfl(base, 0);
    if (base + kK <= FLATCAP)
      for (int j = lane; j < kK; j += 64) flat[base + j] = make_int2(m, j);
  }
}

// ---------------- exact fp32-chain dist per candidate ----------------
__global__ __launch_bounds__(256) void exact_kernel(
    const float* __restrict__ z, const float* __restrict__ emb,
    const float* __restrict__ sz, const float* __restrict__ cw,
    const int2* __restrict__ flat, const int* __restrict__ ccnt,
    unsigned long long* __restrict__ rkey) {
#pragma clang fp contract(off)
  int total = *ccnt;
  if (total > FLATCAP) total = FLATCAP;
  const int stride = gridDim.x * 256;
  for (int i = blockIdx.x * 256 + threadIdx.x; i < total; i += stride) {
    const int2 c = flat[i];
    const int m = c.x, n = c.y;
    const float* zrow = z + (size_t)m * kD;
    const float* wrow = emb + (size_t)n * kD;
    float a = 0.f;
    for (int d4 = 0; d4 < kD; d4 += 4) {
      const float4 zv = *(const float4*)&zrow[d4];
      const float4 wv = *(const float4*)&wrow[d4];
      a = __builtin_fmaf(zv.x, wv.x, a);
      a = __builtin_fmaf(zv.y, wv.y, a);
      a = __builtin_fmaf(zv.z, wv.z, a);
      a = __builtin_fmaf(zv.w, wv.w, a);
    }
    const float u = sz[m] - 2.0f * a;
    const float dist = u + cw[n];
    const unsigned long long key =
        ((unsigned long long)fmap(dist) << 32) | (unsigned)n;
    atomicMin(&rkey[m], key);  // equal dist -> lower n (numpy first-index)
  }
}

// ---------------- finalize idx + hist + z_q_st + commit partials ----------
__global__ __launch_bounds__(256) void finalize_zq(
    const unsigned long long* __restrict__ rkey, const float* __restrict__ z,
    const float* __restrict__ emb, int* __restrict__ idxg,
    float* __restrict__ out_idx, int* __restrict__ hist,
    float* __restrict__ out_zq, double* __restrict__ part) {
#pragma clang fp contract(off)
  const int n = blockIdx.x;
  const int d = threadIdx.x;
  const int k = (int)(rkey[n] & 0xffffffffu);
  if (d == 0) {
    idxg[n] = k;
    out_idx[n] = (float)k;
    atomicAdd(&hist[k], 1);
  }
  const float zv = z[(size_t)n * kD + d];
  const float q = emb[(size_t)k * kD + d];
  out_zq[(size_t)n * kD + d] = zv + (q - zv);
  const float diff = zv - q;
  double v = (double)diff * (double)diff;
#pragma unroll
  for (int m = 32; m; m >>= 1) v += __shfl_xor(v, m);
  __shared__ double p4[4];
  if ((d & 63) == 0) p4[d >> 6] = v;
  __syncthreads();
  if (d == 0) part[n] = p4[0] + p4[1] + p4[2] + p4[3];
}

// ---------------- single-block: commit reduce + newcount + nsum + prefix ----
__global__ __launch_bounds__(256) void mid_k(
    const double* __restrict__ part, float* __restrict__ out_com,
    const int* __restrict__ hist, const float* __restrict__ ec,
    float* __restrict__ out_cnt, double* __restrict__ nsum,
    int* __restrict__ offs, int* __restrict__ cursor) {
#pragma clang fp contract(off)
  const int t = threadIdx.x;
  __shared__ double dtmp[4];
  __shared__ int itmp[256];

  double s = 0.0;
  for (int i = t; i < kN; i += 256) s += part[i];
#pragma unroll
  for (int m = 32; m; m >>= 1) s += __shfl_xor(s, m);
  if ((t & 63) == 0) dtmp[t >> 6] = s;
  __syncthreads();
  if (t == 0)
    out_com[0] = (float)(0.25 * (dtmp[0] + dtmp[1] + dtmp[2] + dtmp[3]) /
                         (double)((size_t)kN * kD));
  __syncthreads();

  const int base = t * 32;
  double ns = 0.0;
  int run = 0;
  for (int c = 0; c < 32; ++c) {
    const int k = base + c;
    const float nc = 0.99f * ec[k] + 0.01f * (float)hist[k];
    out_cnt[k] = nc;
    ns += (double)nc;
    run += hist[k];
  }
  itmp[t] = run;
  __syncthreads();
  for (int off = 1; off < 256; off <<= 1) {
    const int add = (t >= off) ? itmp[t - off] : 0;
    __syncthreads();
    itmp[t] += add;
    __syncthreads();
  }
  int run2 = itmp[t] - run;
  for (int c = 0; c < 32; ++c) {
    const int k = base + c;
    offs[k] = run2;
    cursor[k] = run2;
    run2 += hist[k];
  }
#pragma unroll
  for (int m = 32; m; m >>= 1) ns += __shfl_xor(ns, m);
  if ((t & 63) == 0) dtmp[t >> 6] = ns;
  __syncthreads();
  if (t == 0) *nsum = dtmp[0] + dtmp[1] + dtmp[2] + dtmp[3];
}

// ---------------- scatter rows into per-code lists ----------------
__global__ __launch_bounds__(256) void scatter_k(const int* __restrict__ idxg,
                                                 int* __restrict__ cursor,
                                                 int* __restrict__ rowlist) {
  const int r = blockIdx.x * 256 + threadIdx.x;
  const int k = idxg[r];
  const int pos = atomicAdd(&cursor[k], 1);
  rowlist[pos] = r;
}

// ---------------- new_avg + new_embed via gathered row sums ----------------
__global__ __launch_bounds__(256) void newavg_k(
    const float* __restrict__ z, const float* __restrict__ ea,
    const int* __restrict__ hist, const int* __restrict__ offs,
    const int* __restrict__ rowlist, const float* __restrict__ out_cnt,
    const double* __restrict__ nsum, float* __restrict__ out_emb,
    float* __restrict__ out_avg) {
#pragma clang fp contract(off)
  const int k = blockIdx.x;
  const int d = threadIdx.x;
  const int c = hist[k];
  const int off = offs[k];
  float s = 0.f;
  for (int j = 0; j < c; ++j)
    s += z[(size_t)rowlist[off + j] * kD + d];
  const size_t o = (size_t)k * kD + d;
  const float na = 0.99f * ea[o] + 0.01f * s;
  out_avg[o] = na;
  const float nf = (float)(*nsum);
  const float nc = out_cnt[k];
  const float keps = 0.08192f;  // fl(K * EPS)
  const float cs = (nc + 1e-5f) / (nf + keps) * nf;
  out_emb[o] = na / cs;
}

extern "C" void kernel_launch(void* const* d_in, const int* in_sizes, int n_in,
                              void* d_out, int out_size, void* d_ws, size_t ws_size,
                              hipStream_t stream) {
  const float* z_e       = (const float*)d_in[0];
  const float* embedding = (const float*)d_in[1];
  const float* ema_count = (const float*)d_in[2];
  const float* ema_avg   = (const float*)d_in[3];

  char* ws = (char*)d_ws;
  int*    hist   = (int*)(ws + OFF_HIST);
  double* nsum   = (double*)(ws + OFF_NS);
  unsigned* gcnt = (unsigned*)(ws + OFF_GCNT);
  int*    ccnt   = (int*)(ws + OFF_CCNT);
  unsigned long long* rkey = (unsigned long long*)(ws + OFF_RKEY);
  unsigned* rmin = (unsigned*)(ws + OFF_RMIN);
  float*  sz     = (float*)(ws + OFF_SZ);
  float*  cw     = (float*)(ws + OFF_CW);
  _Float16* z16  = (_Float16*)(ws + OFF_Z16);
  _Float16* w16  = (_Float16*)(ws + OFF_W16);
  int2*   gcand  = (int2*)(ws + OFF_CAND);
  int2*   flat   = (int2*)(ws + OFF_FLAT);
  int*    idxg   = (int*)(ws + OFF_IDX);
  int*    offs   = (int*)(ws + OFF_OFFS);
  int*    cursor = (int*)(ws + OFF_CUR);
  int*    rowlist= (int*)(ws + OFF_ROWL);
  double* part   = (double*)(ws + OFF_PART);

  float* out_zq  = (float*)d_out;
  float* out_com = out_zq + (size_t)kN * kD;
  float* out_idx = out_com + 1;
  float* out_emb = out_idx + kN;
  float* out_cnt = out_emb + (size_t)kK * kD;
  float* out_avg = out_cnt + kK;

  hipMemsetAsync(ws, 0, ZERO_BYTES, stream);
  hipMemsetAsync(ws + OFF_RKEY, 0xFF, FF_BYTES, stream);

  prep2<<<kN / 256 + kK / 256, 256, 0, stream>>>(z_e, embedding, z16, w16, sz,
                                                 cw);
  score_kernel<<<(kN / 128) * (kK / 128), 256, 0, stream>>>(z16, w16, cw, gcnt,
                                                            gcand, rmin);
  compact_kernel<<<kN / 4, 256, 0, stream>>>(gcnt, gcand, rmin, flat, ccnt);
  exact_kernel<<<1024, 256, 0, stream>>>(z_e, embedding, sz, cw, flat, ccnt,
                                         rkey);
  finalize_zq<<<kN, 256, 0, stream>>>(rkey, z_e, embedding, idxg, out_idx,
                                      hist, out_zq, part);
  mid_k<<<1, 256, 0, stream>>>(part, out_com, hist, ema_count, out_cnt, nsum,
                               offs, cursor);
  scatter_k<<<kN / 256, 256, 0, stream>>>(idxg, cursor, rowlist);
  newavg_k<<<kK, 256, 0, stream>>>(z_e, ema_avg, hist, offs, rowlist, out_cnt,
                                   nsum, out_emb, out_avg);
}

// Round 8
// 973.900 us; speedup vs baseline: 1.1027x; 1.1027x over previous
//
#include <hip/hip_runtime.h>

// VectorQuantizerEMA  N=32768 K=8192 D=256  fp32
// Outputs: z_q_st[N*D], commitment[1], idx[N], new_embed[K*D], new_count[K], new_avg[K*D]
//
// Score side is a deterministic TWO-PHASE fp16 MFMA GEMM (z16 * (w*2^14)16):
//   Pass A: score = cw - 2^-13*acc; block row-min -> fire-and-forget global
//           atomicMin into rmin_map (no return, no races that matter).
//   Pass B: same GEMM; thr = final global min + W (plain loads); windowed
//           candidate inserts (~1.3/row, no overflow).
// Then: compact -> exact fp32-chain dist (bit-exact vs numpy/OpenBLAS) ->
// atomicMin (fmap(dist)<<32|n) = numpy first-index tie-break. EMA epilogue
// via inverted index.

typedef _Float16 half8 __attribute__((ext_vector_type(8)));
typedef _Float16 half4 __attribute__((ext_vector_type(4)));
typedef __attribute__((ext_vector_type(4))) float floatx4;

namespace {
constexpr int kN = 32768;
constexpr int kK = 8192;
constexpr int kD = 256;
constexpr int CAP = 64;
constexpr int FLATCAP = 1 << 21;
constexpr float WWIN = 2.0e-4f;  // containment needs ~8.5e-5; 2.3x margin

// ---- workspace layout (bytes) ----
constexpr size_t OFF_HIST = 0;                                // int K
constexpr size_t OFF_NS   = OFF_HIST + (size_t)kK * 4;        // double
constexpr size_t OFF_GCNT = OFF_NS + 8;                       // uint N
constexpr size_t OFF_CCNT = OFF_GCNT + (size_t)kN * 4;        // int
constexpr size_t ZERO_BYTES = OFF_CCNT + 8;
constexpr size_t OFF_RKEY = (ZERO_BYTES + 63) & ~(size_t)63;  // ull N   } one
constexpr size_t OFF_RMIN = OFF_RKEY + (size_t)kN * 8;        // uint N  } 0xFF memset
constexpr size_t FF_BYTES = (size_t)kN * 12;
constexpr size_t OFF_SZ   = OFF_RMIN + (size_t)kN * 4;        // float N
constexpr size_t OFF_CW   = OFF_SZ + (size_t)kN * 4;          // float K
constexpr size_t OFF_Z16  = OFF_CW + (size_t)kK * 4;          // f16 N*D
constexpr size_t OFF_W16  = OFF_Z16 + (size_t)kN * kD * 2;    // f16 K*D
constexpr size_t OFF_CAND = OFF_W16 + (size_t)kK * kD * 2;    // int2 N*CAP
constexpr size_t OFF_FLAT = OFF_CAND + (size_t)kN * CAP * 8;  // int2 FLATCAP
constexpr size_t OFF_IDX  = OFF_FLAT + (size_t)FLATCAP * 8;   // int N
constexpr size_t OFF_OFFS = OFF_IDX + (size_t)kN * 4;         // int K
constexpr size_t OFF_CUR  = OFF_OFFS + (size_t)kK * 4;        // int K
constexpr size_t OFF_ROWL = OFF_CUR + (size_t)kK * 4;         // int N
constexpr size_t OFF_PART = OFF_ROWL + (size_t)kN * 4;        // double N
} // namespace

__device__ __forceinline__ unsigned fmap(float f) {
  unsigned u = __float_as_uint(f);
  return (u & 0x80000000u) ? ~u : (u | 0x80000000u);
}
__device__ __forceinline__ float funmap(unsigned m) {
  unsigned u = (m & 0x80000000u) ? (m & 0x7fffffffu) : ~m;
  return __uint_as_float(u);
}
__device__ __forceinline__ void gload16(const void* g, void* l) {
  __builtin_amdgcn_global_load_lds(
      (const __attribute__((address_space(1))) unsigned int*)g,
      (__attribute__((address_space(3))) unsigned int*)l, 16, 0, 0);
}

// ---------------- numpy AVX512 pairwise sum of squares ----------------
__device__ __forceinline__ float pw_block128_sq(const float* __restrict__ p) {
#pragma clang fp contract(off)
  float u[16];
#pragma unroll
  for (int l = 0; l < 16; ++l) {
    const float x0 = p[l] * p[l];
    const float x1 = p[16 + l] * p[16 + l];
    const float x2 = p[32 + l] * p[32 + l];
    const float x3 = p[48 + l] * p[48 + l];
    const float x4 = p[64 + l] * p[64 + l];
    const float x5 = p[80 + l] * p[80 + l];
    const float x6 = p[96 + l] * p[96 + l];
    const float x7 = p[112 + l] * p[112 + l];
    u[l] = ((x0 + x1) + (x2 + x3)) + ((x4 + x5) + (x6 + x7));
  }
  float t1[8], t2[4], t3[2];
#pragma unroll
  for (int l = 0; l < 8; ++l) t1[l] = u[l] + u[l + 8];
#pragma unroll
  for (int l = 0; l < 4; ++l) t2[l] = t1[l] + t1[l + 4];
#pragma unroll
  for (int l = 0; l < 2; ++l) t3[l] = t2[l] + t2[l + 2];
  return t3[0] + t3[1];
}

// ---------------- fused fp16 convert + numpy-order row sums (z and w) ------
__global__ __launch_bounds__(256) void prep2(const float* __restrict__ z,
                                             const float* __restrict__ w,
                                             _Float16* __restrict__ z16,
                                             _Float16* __restrict__ w16,
                                             float* __restrict__ sz,
                                             float* __restrict__ cw) {
  const bool isz = (blockIdx.x < kN / 256);
  const int b = isz ? blockIdx.x : blockIdx.x - kN / 256;
  const int nblocks = isz ? kN / 256 : kK / 256;
  const int nrows = isz ? kN : kK;
  const float scale = isz ? 1.0f : 16384.0f;
  const float* x = isz ? z : w;
  _Float16* out16 = isz ? z16 : w16;
  float* sums = isz ? sz : cw;

  const int gid = b * 256 + threadIdx.x;
  const int gtot = nblocks * 256;
  const int nf4 = nrows * (kD / 4);
  for (int i = gid; i < nf4; i += gtot) {
    const float4 v = ((const float4*)x)[i];
    half4 h;
    h.x = (_Float16)(v.x * scale);
    h.y = (_Float16)(v.y * scale);
    h.z = (_Float16)(v.z * scale);
    h.w = (_Float16)(v.w * scale);
    ((half4*)out16)[i] = h;
  }
  for (int r = gid; r < nrows; r += gtot) {
    const float* p = x + (size_t)r * kD;
    sums[r] = pw_block128_sq(p) + pw_block128_sq(p + 128);
  }
}

// ---------------- two-phase MFMA score pass: 128x128 tile, BK=64 -----------
// grid 16384, mtile INNER (blockIdx&255) so concurrent blocks touch disjoint
// rmin_map/gcnt rows; ntile outer shares the B-tile in L2.
template <bool INSERT>
__global__ __launch_bounds__(256, 4) void score_pass(
    const _Float16* __restrict__ z16, const _Float16* __restrict__ w16,
    const float* __restrict__ cw, unsigned* __restrict__ rmin_map,
    unsigned* __restrict__ gcnt, int2* __restrict__ gcand) {
  __shared__ _Float16 As[128 * 64];  // 16 KB, XOR-swizzled 16B chunks (8/row)
  __shared__ _Float16 Bs[128 * 64];  // 16 KB

  const int tid = threadIdx.x;
  const int wid = tid >> 6;
  const int lane = tid & 63;
  const int l16 = lane & 15;
  const int quad = lane >> 4;
  const int m0 = (blockIdx.x & 255) * 128;
  const int n0 = (blockIdx.x >> 8) * 128;
  const int rowbase = (wid >> 1) * 64;
  const int colbase = (wid & 1) * 64;

  floatx4 acc[4][4];
#pragma unroll
  for (int a = 0; a < 4; ++a)
#pragma unroll
    for (int b = 0; b < 4; ++b) acc[a][b] = (floatx4){0.f, 0.f, 0.f, 0.f};

  for (int kt = 0; kt < 4; ++kt) {
    const int d0 = kt * 64;
    __syncthreads();  // prior-iter LDS reads complete before overwrite
#pragma unroll
    for (int p = 0; p < 4; ++p) {  // A: 128 rows x 64 d
      const int q = p * 4 + wid;
      const int r = q * 8 + (lane >> 3);
      const int c = (lane & 7) ^ (r & 7);
      gload16(z16 + (size_t)(m0 + r) * kD + d0 + c * 8, &As[q * 512]);
    }
#pragma unroll
    for (int p = 0; p < 4; ++p) {  // B: 128 codes x 64 d
      const int q = p * 4 + wid;
      const int r = q * 8 + (lane >> 3);
      const int c = (lane & 7) ^ (r & 7);
      gload16(w16 + (size_t)(n0 + r) * kD + d0 + c * 8, &Bs[q * 512]);
    }
    __syncthreads();  // drain staging
#pragma unroll
    for (int kc = 0; kc < 2; ++kc) {
      half8 af[4], bfr[4];
#pragma unroll
      for (int mt = 0; mt < 4; ++mt) {
        const int row = rowbase + mt * 16 + l16;
        const int j = (kc * 4 + quad) ^ (row & 7);
        af[mt] = *(const half8*)&As[row * 64 + j * 8];
      }
#pragma unroll
      for (int nt = 0; nt < 4; ++nt) {
        const int row = colbase + nt * 16 + l16;
        const int j = (kc * 4 + quad) ^ (row & 7);
        bfr[nt] = *(const half8*)&Bs[row * 64 + j * 8];
      }
#pragma unroll
      for (int mt = 0; mt < 4; ++mt)
#pragma unroll
        for (int nt = 0; nt < 4; ++nt)
          acc[mt][nt] = __builtin_amdgcn_mfma_f32_16x16x32_f16(
              af[mt], bfr[nt], acc[mt][nt], 0, 0, 0);
    }
  }

  // ---- scores: w scaled by 2^14 -> -2*2^-14 = -2^-13 exactly ----
  float cwv[4];
#pragma unroll
  for (int nt = 0; nt < 4; ++nt)
    cwv[nt] = cw[n0 + colbase + nt * 16 + l16];

  if constexpr (!INSERT) {
    // -------- pass A: block row-min -> fire-and-forget global atomicMin ----
    __shared__ unsigned pairmin[4][64];
#pragma unroll
    for (int mt = 0; mt < 4; ++mt)
#pragma unroll
      for (int r = 0; r < 4; ++r) {
        float mn = 3.4e38f;
#pragma unroll
        for (int nt = 0; nt < 4; ++nt)
          mn = fminf(mn, fmaf(acc[mt][nt][r], -1.220703125e-4f, cwv[nt]));
#pragma unroll
        for (int off = 1; off < 16; off <<= 1)
          mn = fminf(mn, __shfl_xor(mn, off));
        if (l16 == 0) pairmin[wid][mt * 16 + quad * 4 + r] = fmap(mn);
      }
    __syncthreads();
    if ((wid & 1) == 0) {
      const unsigned v =
          min(pairmin[wid][lane], pairmin[wid + 1][lane]);
      atomicMin(&rmin_map[m0 + rowbase + lane], v);  // no return use
    }
  } else {
    // -------- pass B: tight thresholds (plain loads), windowed inserts -----
#pragma unroll
    for (int mt = 0; mt < 4; ++mt) {
#pragma unroll
      for (int r = 0; r < 4; ++r) {
        const int m = m0 + rowbase + mt * 16 + quad * 4 + r;
        const float thr = funmap(rmin_map[m]) + WWIN;
#pragma unroll
        for (int nt = 0; nt < 4; ++nt) {
          const float s = fmaf(acc[mt][nt][r], -1.220703125e-4f, cwv[nt]);
          if (s <= thr) {
            const int n = n0 + colbase + nt * 16 + l16;
            const unsigned pos = atomicAdd(&gcnt[m], 1u);
            if (pos < CAP)
              gcand[(size_t)m * CAP + pos] = make_int2(__float_as_int(s), n);
          }
        }
      }
    }
  }
}

// ---------------- compact candidates into flat list (wave per row) --------
__global__ __launch_bounds__(256) void compact_kernel(
    const unsigned* __restrict__ gcnt, const int2* __restrict__ gcand,
    const unsigned* __restrict__ rmin_map, int2* __restrict__ flat,
    int* __restrict__ ccnt) {
  const int wid = threadIdx.x >> 6;
  const int lane = threadIdx.x & 63;
  const int m = blockIdx.x * 4 + wid;
  const unsigned cnt = gcnt[m];
  if (cnt <= (unsigned)CAP) {
    const float thr = funmap(rmin_map[m]) + WWIN;
    int n = 0;
    bool keep = false;
    if (lane < (int)cnt) {
      const int2 cd = gcand[(size_t)m * CAP + lane];
      keep = (__int_as_float(cd.x) <= thr);
      n = cd.y;
    }
    const unsigned long long mask = __ballot(keep);
    const int tot = __popcll(mask);
    int base = 0;
    if (lane == 0 && tot) base = atomicAdd(ccnt, tot);
    base = __shfl(base, 0);
    if (keep && base + tot <= FLATCAP) {
      const int rank = __popcll(mask & ((1ull << lane) - 1ull));
      flat[base + rank] = make_int2(m, n);
    }
  } else {
    // overflow (should never happen now): full-K exact scan
    int base = 0;
    if (lane == 0) base = atomicAdd(ccnt, kK);
    base = __shfl(base, 0);
    if (base + kK <= FLATCAP)
      for (int j = lane; j < kK; j += 64) flat[base + j] = make_int2(m, j);
  }
}

// ---------------- exact fp32-chain dist per candidate ----------------
__global__ __launch_bounds__(256) void exact_kernel(
    const float* __restrict__ z, const float* __restrict__ emb,
    const float* __restrict__ sz, const float* __restrict__ cw,
    const int2* __restrict__ flat, const int* __restrict__ ccnt,
    unsigned long long* __restrict__ rkey) {
#pragma clang fp contract(off)
  int total = *ccnt;
  if (total > FLATCAP) total = FLATCAP;
  const int stride = gridDim.x * 256;
  for (int i = blockIdx.x * 256 + threadIdx.x; i < total; i += stride) {
    const int2 c = flat[i];
    const int m = c.x, n = c.y;
    const float* zrow = z + (size_t)m * kD;
    const float* wrow = emb + (size_t)n * kD;
    float a = 0.f;
    for (int d4 = 0; d4 < kD; d4 += 4) {
      const float4 zv = *(const float4*)&zrow[d4];
      const float4 wv = *(const float4*)&wrow[d4];
      a = __builtin_fmaf(zv.x, wv.x, a);
      a = __builtin_fmaf(zv.y, wv.y, a);
      a = __builtin_fmaf(zv.z, wv.z, a);
      a = __builtin_fmaf(zv.w, wv.w, a);
    }
    const float u = sz[m] - 2.0f * a;
    const float dist = u + cw[n];
    const unsigned long long key =
        ((unsigned long long)fmap(dist) << 32) | (unsigned)n;
    atomicMin(&rkey[m], key);  // equal dist -> lower n (numpy first-index)
  }
}

// ---------------- finalize idx + hist + z_q_st + commit partials ----------
__global__ __launch_bounds__(256) void finalize_zq(
    const unsigned long long* __restrict__ rkey, const float* __restrict__ z,
    const float* __restrict__ emb, int* __restrict__ idxg,
    float* __restrict__ out_idx, int* __restrict__ hist,
    float* __restrict__ out_zq, double* __restrict__ part) {
#pragma clang fp contract(off)
  const int n = blockIdx.x;
  const int d = threadIdx.x;
  const int k = (int)(rkey[n] & 0xffffffffu);
  if (d == 0) {
    idxg[n] = k;
    out_idx[n] = (float)k;
    atomicAdd(&hist[k], 1);
  }
  const float zv = z[(size_t)n * kD + d];
  const float q = emb[(size_t)k * kD + d];
  out_zq[(size_t)n * kD + d] = zv + (q - zv);
  const float diff = zv - q;
  double v = (double)diff * (double)diff;
#pragma unroll
  for (int m = 32; m; m >>= 1) v += __shfl_xor(v, m);
  __shared__ double p4[4];
  if ((d & 63) == 0) p4[d >> 6] = v;
  __syncthreads();
  if (d == 0) part[n] = p4[0] + p4[1] + p4[2] + p4[3];
}

// ---------------- single-block: commit reduce + newcount + nsum + prefix ----
__global__ __launch_bounds__(256) void mid_k(
    const double* __restrict__ part, float* __restrict__ out_com,
    const int* __restrict__ hist, const float* __restrict__ ec,
    float* __restrict__ out_cnt, double* __restrict__ nsum,
    int* __restrict__ offs, int* __restrict__ cursor) {
#pragma clang fp contract(off)
  const int t = threadIdx.x;
  __shared__ double dtmp[4];
  __shared__ int itmp[256];

  double s = 0.0;
  for (int i = t; i < kN; i += 256) s += part[i];
#pragma unroll
  for (int m = 32; m; m >>= 1) s += __shfl_xor(s, m);
  if ((t & 63) == 0) dtmp[t >> 6] = s;
  __syncthreads();
  if (t == 0)
    out_com[0] = (float)(0.25 * (dtmp[0] + dtmp[1] + dtmp[2] + dtmp[3]) /
                         (double)((size_t)kN * kD));
  __syncthreads();

  const int base = t * 32;
  double ns = 0.0;
  int run = 0;
  for (int c = 0; c < 32; ++c) {
    const int k = base + c;
    const float nc = 0.99f * ec[k] + 0.01f * (float)hist[k];
    out_cnt[k] = nc;
    ns += (double)nc;
    run += hist[k];
  }
  itmp[t] = run;
  __syncthreads();
  for (int off = 1; off < 256; off <<= 1) {
    const int add = (t >= off) ? itmp[t - off] : 0;
    __syncthreads();
    itmp[t] += add;
    __syncthreads();
  }
  int run2 = itmp[t] - run;
  for (int c = 0; c < 32; ++c) {
    const int k = base + c;
    offs[k] = run2;
    cursor[k] = run2;
    run2 += hist[k];
  }
#pragma unroll
  for (int m = 32; m; m >>= 1) ns += __shfl_xor(ns, m);
  if ((t & 63) == 0) dtmp[t >> 6] = ns;
  __syncthreads();
  if (t == 0) *nsum = dtmp[0] + dtmp[1] + dtmp[2] + dtmp[3];
}

// ---------------- scatter rows into per-code lists ----------------
__global__ __launch_bounds__(256) void scatter_k(const int* __restrict__ idxg,
                                                 int* __restrict__ cursor,
                                                 int* __restrict__ rowlist) {
  const int r = blockIdx.x * 256 + threadIdx.x;
  const int k = idxg[r];
  const int pos = atomicAdd(&cursor[k], 1);
  rowlist[pos] = r;
}

// ---------------- new_avg + new_embed via gathered row sums ----------------
__global__ __launch_bounds__(256) void newavg_k(
    const float* __restrict__ z, const float* __restrict__ ea,
    const int* __restrict__ hist, const int* __restrict__ offs,
    const int* __restrict__ rowlist, const float* __restrict__ out_cnt,
    const double* __restrict__ nsum, float* __restrict__ out_emb,
    float* __restrict__ out_avg) {
#pragma clang fp contract(off)
  const int k = blockIdx.x;
  const int d = threadIdx.x;
  const int c = hist[k];
  const int off = offs[k];
  float s = 0.f;
  for (int j = 0; j < c; ++j)
    s += z[(size_t)rowlist[off + j] * kD + d];
  const size_t o = (size_t)k * kD + d;
  const float na = 0.99f * ea[o] + 0.01f * s;
  out_avg[o] = na;
  const float nf = (float)(*nsum);
  const float nc = out_cnt[k];
  const float keps = 0.08192f;  // fl(K * EPS)
  const float cs = (nc + 1e-5f) / (nf + keps) * nf;
  out_emb[o] = na / cs;
}

extern "C" void kernel_launch(void* const* d_in, const int* in_sizes, int n_in,
                              void* d_out, int out_size, void* d_ws, size_t ws_size,
                              hipStream_t stream) {
  const float* z_e       = (const float*)d_in[0];
  const float* embedding = (const float*)d_in[1];
  const float* ema_count = (const float*)d_in[2];
  const float* ema_avg   = (const float*)d_in[3];

  char* ws = (char*)d_ws;
  int*    hist   = (int*)(ws + OFF_HIST);
  double* nsum   = (double*)(ws + OFF_NS);
  unsigned* gcnt = (unsigned*)(ws + OFF_GCNT);
  int*    ccnt   = (int*)(ws + OFF_CCNT);
  unsigned long long* rkey = (unsigned long long*)(ws + OFF_RKEY);
  unsigned* rmin = (unsigned*)(ws + OFF_RMIN);
  float*  sz     = (float*)(ws + OFF_SZ);
  float*  cw     = (float*)(ws + OFF_CW);
  _Float16* z16  = (_Float16*)(ws + OFF_Z16);
  _Float16* w16  = (_Float16*)(ws + OFF_W16);
  int2*   gcand  = (int2*)(ws + OFF_CAND);
  int2*   flat   = (int2*)(ws + OFF_FLAT);
  int*    idxg   = (int*)(ws + OFF_IDX);
  int*    offs   = (int*)(ws + OFF_OFFS);
  int*    cursor = (int*)(ws + OFF_CUR);
  int*    rowlist= (int*)(ws + OFF_ROWL);
  double* part   = (double*)(ws + OFF_PART);

  float* out_zq  = (float*)d_out;
  float* out_com = out_zq + (size_t)kN * kD;
  float* out_idx = out_com + 1;
  float* out_emb = out_idx + kN;
  float* out_cnt = out_emb + (size_t)kK * kD;
  float* out_avg = out_cnt + kK;

  hipMemsetAsync(ws, 0, ZERO_BYTES, stream);
  hipMemsetAsync(ws + OFF_RKEY, 0xFF, FF_BYTES, stream);

  prep2<<<kN / 256 + kK / 256, 256, 0, stream>>>(z_e, embedding, z16, w16, sz,
                                                 cw);
  score_pass<false><<<(kN / 128) * (kK / 128), 256, 0, stream>>>(
      z16, w16, cw, rmin, nullptr, nullptr);
  score_pass<true><<<(kN / 128) * (kK / 128), 256, 0, stream>>>(
      z16, w16, cw, rmin, gcnt, gcand);
  compact_kernel<<<kN / 4, 256, 0, stream>>>(gcnt, gcand, rmin, flat, ccnt);
  exact_kernel<<<512, 256, 0, stream>>>(z_e, embedding, sz, cw, flat, ccnt,
                                        rkey);
  finalize_zq<<<kN, 256, 0, stream>>>(rkey, z_e, embedding, idxg, out_idx,
                                      hist, out_zq, part);
  mid_k<<<1, 256, 0, stream>>>(part, out_com, hist, ema_count, out_cnt, nsum,
                               offs, cursor);
  scatter_k<<<kN / 256, 256, 0, stream>>>(idxg, cursor, rowlist);
  newavg_k<<<kK, 256, 0, stream>>>(z_e, ema_avg, hist, offs, rowlist, out_cnt,
                                   nsum, out_emb, out_avg);
}

// Round 9
// 819.478 us; speedup vs baseline: 1.3104x; 1.1884x over previous
//
#include <hip/hip_runtime.h>

// VectorQuantizerEMA  N=32768 K=8192 D=256  fp32
// Outputs: z_q_st[N*D], commitment[1], idx[N], new_embed[K*D], new_count[K], new_avg[K*D]
//
// Deterministic two-phase fp16 MFMA score GEMM (z16 * (w*2^14)16):
//   Pass A: score = cw - 2^-13*acc; block row-min -> fire-and-forget global
//           atomicMin into rmin_map.
//   Pass B: same GEMM; thr = FINAL global min + W (plain loads); candidates
//           inserted DIRECTLY into a 64-way segmented flat list (no single
//           hot counter, no compaction kernel).
// Then: exact fp32-chain dist per candidate (bit-exact vs numpy/OpenBLAS) ->
// atomicMin (fmap(dist)<<32|n) = numpy first-index tie-break. EMA epilogue
// via inverted index.

typedef _Float16 half8 __attribute__((ext_vector_type(8)));
typedef _Float16 half4 __attribute__((ext_vector_type(4)));
typedef __attribute__((ext_vector_type(4))) float floatx4;

namespace {
constexpr int kN = 32768;
constexpr int kK = 8192;
constexpr int kD = 256;
constexpr int NSEG = 64;
constexpr int SEGCAP = 32768;      // int2 per segment; 64*32768 = 2M entries
constexpr float WWIN = 2.0e-4f;    // containment needs ~8.5e-5; 2.3x margin

// ---- workspace layout (bytes) ----
constexpr size_t OFF_HIST = 0;                                // int K
constexpr size_t OFF_NS   = OFF_HIST + (size_t)kK * 4;        // double
constexpr size_t OFF_SEG  = OFF_NS + 8;                       // uint NSEG
constexpr size_t ZERO_BYTES = OFF_SEG + (size_t)NSEG * 4;
constexpr size_t OFF_RKEY = (ZERO_BYTES + 63) & ~(size_t)63;  // ull N   } one
constexpr size_t OFF_RMIN = OFF_RKEY + (size_t)kN * 8;        // uint N  } 0xFF memset
constexpr size_t FF_BYTES = (size_t)kN * 12;
constexpr size_t OFF_SZ   = OFF_RMIN + (size_t)kN * 4;        // float N
constexpr size_t OFF_CW   = OFF_SZ + (size_t)kN * 4;          // float K
constexpr size_t OFF_Z16  = OFF_CW + (size_t)kK * 4;          // f16 N*D
constexpr size_t OFF_W16  = OFF_Z16 + (size_t)kN * kD * 2;    // f16 K*D
constexpr size_t OFF_FLAT = OFF_W16 + (size_t)kK * kD * 2;    // int2 NSEG*SEGCAP
constexpr size_t OFF_IDX  = OFF_FLAT + (size_t)NSEG * SEGCAP * 8;  // int N
constexpr size_t OFF_OFFS = OFF_IDX + (size_t)kN * 4;         // int K
constexpr size_t OFF_CUR  = OFF_OFFS + (size_t)kK * 4;        // int K
constexpr size_t OFF_ROWL = OFF_CUR + (size_t)kK * 4;         // int N
constexpr size_t OFF_PART = OFF_ROWL + (size_t)kN * 4;        // double N
} // namespace

__device__ __forceinline__ unsigned fmap(float f) {
  unsigned u = __float_as_uint(f);
  return (u & 0x80000000u) ? ~u : (u | 0x80000000u);
}
__device__ __forceinline__ float funmap(unsigned m) {
  unsigned u = (m & 0x80000000u) ? (m & 0x7fffffffu) : ~m;
  return __uint_as_float(u);
}
__device__ __forceinline__ void gload16(const void* g, void* l) {
  __builtin_amdgcn_global_load_lds(
      (const __attribute__((address_space(1))) unsigned int*)g,
      (__attribute__((address_space(3))) unsigned int*)l, 16, 0, 0);
}

// ---------------- numpy AVX512 pairwise sum of squares ----------------
__device__ __forceinline__ float pw_block128_sq(const float* __restrict__ p) {
#pragma clang fp contract(off)
  float u[16];
#pragma unroll
  for (int l = 0; l < 16; ++l) {
    const float x0 = p[l] * p[l];
    const float x1 = p[16 + l] * p[16 + l];
    const float x2 = p[32 + l] * p[32 + l];
    const float x3 = p[48 + l] * p[48 + l];
    const float x4 = p[64 + l] * p[64 + l];
    const float x5 = p[80 + l] * p[80 + l];
    const float x6 = p[96 + l] * p[96 + l];
    const float x7 = p[112 + l] * p[112 + l];
    u[l] = ((x0 + x1) + (x2 + x3)) + ((x4 + x5) + (x6 + x7));
  }
  float t1[8], t2[4], t3[2];
#pragma unroll
  for (int l = 0; l < 8; ++l) t1[l] = u[l] + u[l + 8];
#pragma unroll
  for (int l = 0; l < 4; ++l) t2[l] = t1[l] + t1[l + 4];
#pragma unroll
  for (int l = 0; l < 2; ++l) t3[l] = t2[l] + t2[l + 2];
  return t3[0] + t3[1];
}

// ---------------- fused fp16 convert + numpy-order row sums (z and w) ------
__global__ __launch_bounds__(256) void prep2(const float* __restrict__ z,
                                             const float* __restrict__ w,
                                             _Float16* __restrict__ z16,
                                             _Float16* __restrict__ w16,
                                             float* __restrict__ sz,
                                             float* __restrict__ cw) {
  const bool isz = (blockIdx.x < kN / 256);
  const int b = isz ? blockIdx.x : blockIdx.x - kN / 256;
  const int nblocks = isz ? kN / 256 : kK / 256;
  const int nrows = isz ? kN : kK;
  const float scale = isz ? 1.0f : 16384.0f;
  const float* x = isz ? z : w;
  _Float16* out16 = isz ? z16 : w16;
  float* sums = isz ? sz : cw;

  const int gid = b * 256 + threadIdx.x;
  const int gtot = nblocks * 256;
  const int nf4 = nrows * (kD / 4);
  for (int i = gid; i < nf4; i += gtot) {
    const float4 v = ((const float4*)x)[i];
    half4 h;
    h.x = (_Float16)(v.x * scale);
    h.y = (_Float16)(v.y * scale);
    h.z = (_Float16)(v.z * scale);
    h.w = (_Float16)(v.w * scale);
    ((half4*)out16)[i] = h;
  }
  for (int r = gid; r < nrows; r += gtot) {
    const float* p = x + (size_t)r * kD;
    sums[r] = pw_block128_sq(p) + pw_block128_sq(p + 128);
  }
}

// ---------------- two-phase MFMA score pass: 128x128 tile, BK=64 -----------
// grid 16384, mtile INNER (blockIdx&255) so concurrent blocks touch disjoint
// rmin_map rows; ntile outer shares the B-tile in L2.
template <bool INSERT>
__global__ __launch_bounds__(256, 4) void score_pass(
    const _Float16* __restrict__ z16, const _Float16* __restrict__ w16,
    const float* __restrict__ cw, unsigned* __restrict__ rmin_map,
    unsigned* __restrict__ segcnt, int2* __restrict__ flat) {
  __shared__ _Float16 As[128 * 64];  // 16 KB, XOR-swizzled 16B chunks (8/row)
  __shared__ _Float16 Bs[128 * 64];  // 16 KB

  const int tid = threadIdx.x;
  const int wid = tid >> 6;
  const int lane = tid & 63;
  const int l16 = lane & 15;
  const int quad = lane >> 4;
  const int m0 = (blockIdx.x & 255) * 128;
  const int n0 = (blockIdx.x >> 8) * 128;
  const int rowbase = (wid >> 1) * 64;
  const int colbase = (wid & 1) * 64;

  floatx4 acc[4][4];
#pragma unroll
  for (int a = 0; a < 4; ++a)
#pragma unroll
    for (int b = 0; b < 4; ++b) acc[a][b] = (floatx4){0.f, 0.f, 0.f, 0.f};

  for (int kt = 0; kt < 4; ++kt) {
    const int d0 = kt * 64;
    __syncthreads();  // prior-iter LDS reads complete before overwrite
#pragma unroll
    for (int p = 0; p < 4; ++p) {  // A: 128 rows x 64 d
      const int q = p * 4 + wid;
      const int r = q * 8 + (lane >> 3);
      const int c = (lane & 7) ^ (r & 7);
      gload16(z16 + (size_t)(m0 + r) * kD + d0 + c * 8, &As[q * 512]);
    }
#pragma unroll
    for (int p = 0; p < 4; ++p) {  // B: 128 codes x 64 d
      const int q = p * 4 + wid;
      const int r = q * 8 + (lane >> 3);
      const int c = (lane & 7) ^ (r & 7);
      gload16(w16 + (size_t)(n0 + r) * kD + d0 + c * 8, &Bs[q * 512]);
    }
    __syncthreads();  // drain staging
#pragma unroll
    for (int kc = 0; kc < 2; ++kc) {
      half8 af[4], bfr[4];
#pragma unroll
      for (int mt = 0; mt < 4; ++mt) {
        const int row = rowbase + mt * 16 + l16;
        const int j = (kc * 4 + quad) ^ (row & 7);
        af[mt] = *(const half8*)&As[row * 64 + j * 8];
      }
#pragma unroll
      for (int nt = 0; nt < 4; ++nt) {
        const int row = colbase + nt * 16 + l16;
        const int j = (kc * 4 + quad) ^ (row & 7);
        bfr[nt] = *(const half8*)&Bs[row * 64 + j * 8];
      }
#pragma unroll
      for (int mt = 0; mt < 4; ++mt)
#pragma unroll
        for (int nt = 0; nt < 4; ++nt)
          acc[mt][nt] = __builtin_amdgcn_mfma_f32_16x16x32_f16(
              af[mt], bfr[nt], acc[mt][nt], 0, 0, 0);
    }
  }

  // ---- scores: w scaled by 2^14 -> -2*2^-14 = -2^-13 exactly ----
  float cwv[4];
#pragma unroll
  for (int nt = 0; nt < 4; ++nt)
    cwv[nt] = cw[n0 + colbase + nt * 16 + l16];

  if constexpr (!INSERT) {
    // -------- pass A: block row-min -> fire-and-forget global atomicMin ----
    __shared__ unsigned pairmin[4][64];
#pragma unroll
    for (int mt = 0; mt < 4; ++mt)
#pragma unroll
      for (int r = 0; r < 4; ++r) {
        float mn = 3.4e38f;
#pragma unroll
        for (int nt = 0; nt < 4; ++nt)
          mn = fminf(mn, fmaf(acc[mt][nt][r], -1.220703125e-4f, cwv[nt]));
#pragma unroll
        for (int off = 1; off < 16; off <<= 1)
          mn = fminf(mn, __shfl_xor(mn, off));
        if (l16 == 0) pairmin[wid][mt * 16 + quad * 4 + r] = fmap(mn);
      }
    __syncthreads();
    if ((wid & 1) == 0) {
      const unsigned v = min(pairmin[wid][lane], pairmin[wid + 1][lane]);
      atomicMin(&rmin_map[m0 + rowbase + lane], v);  // no return use
    }
  } else {
    // -------- pass B: final thresholds (plain loads), direct segmented insert
    const int bucket = blockIdx.x & (NSEG - 1);
#pragma unroll
    for (int mt = 0; mt < 4; ++mt) {
#pragma unroll
      for (int r = 0; r < 4; ++r) {
        const int m = m0 + rowbase + mt * 16 + quad * 4 + r;
        const float thr = funmap(rmin_map[m]) + WWIN;
#pragma unroll
        for (int nt = 0; nt < 4; ++nt) {
          const float s = fmaf(acc[mt][nt][r], -1.220703125e-4f, cwv[nt]);
          if (s <= thr) {
            const int n = n0 + colbase + nt * 16 + l16;
            const unsigned pos = atomicAdd(&segcnt[bucket], 1u);
            if (pos < (unsigned)SEGCAP)
              flat[(size_t)bucket * SEGCAP + pos] = make_int2(m, n);
          }
        }
      }
    }
  }
}

// ---------------- exact fp32-chain dist per candidate (segmented) ----------
__global__ __launch_bounds__(256) void exact_kernel(
    const float* __restrict__ z, const float* __restrict__ emb,
    const float* __restrict__ sz, const float* __restrict__ cw,
    const int2* __restrict__ flat, const unsigned* __restrict__ segcnt,
    unsigned long long* __restrict__ rkey) {
#pragma clang fp contract(off)
  const int i = blockIdx.x * 256 + threadIdx.x;
  const int seg = i >> 15;           // SEGCAP = 32768
  const int off = i & (SEGCAP - 1);
  unsigned cnt = segcnt[seg];
  if (cnt > (unsigned)SEGCAP) cnt = SEGCAP;
  if (off >= (int)cnt) return;
  const int2 c = flat[(size_t)seg * SEGCAP + off];
  const int m = c.x, n = c.y;
  const float* zrow = z + (size_t)m * kD;
  const float* wrow = emb + (size_t)n * kD;
  float a = 0.f;
  for (int d4 = 0; d4 < kD; d4 += 4) {
    const float4 zv = *(const float4*)&zrow[d4];
    const float4 wv = *(const float4*)&wrow[d4];
    a = __builtin_fmaf(zv.x, wv.x, a);
    a = __builtin_fmaf(zv.y, wv.y, a);
    a = __builtin_fmaf(zv.z, wv.z, a);
    a = __builtin_fmaf(zv.w, wv.w, a);
  }
  const float u = sz[m] - 2.0f * a;
  const float dist = u + cw[n];
  const unsigned long long key =
      ((unsigned long long)fmap(dist) << 32) | (unsigned)n;
  atomicMin(&rkey[m], key);  // equal dist -> lower n (numpy first-index)
}

// ---------------- finalize idx + hist + z_q_st + commit partials ----------
__global__ __launch_bounds__(256) void finalize_zq(
    const unsigned long long* __restrict__ rkey, const float* __restrict__ z,
    const float* __restrict__ emb, int* __restrict__ idxg,
    float* __restrict__ out_idx, int* __restrict__ hist,
    float* __restrict__ out_zq, double* __restrict__ part) {
#pragma clang fp contract(off)
  const int n = blockIdx.x;
  const int d = threadIdx.x;
  const int k = (int)(rkey[n] & 0xffffffffu);
  if (d == 0) {
    idxg[n] = k;
    out_idx[n] = (float)k;
    atomicAdd(&hist[k], 1);
  }
  const float zv = z[(size_t)n * kD + d];
  const float q = emb[(size_t)k * kD + d];
  out_zq[(size_t)n * kD + d] = zv + (q - zv);
  const float diff = zv - q;
  double v = (double)diff * (double)diff;
#pragma unroll
  for (int m = 32; m; m >>= 1) v += __shfl_xor(v, m);
  __shared__ double p4[4];
  if ((d & 63) == 0) p4[d >> 6] = v;
  __syncthreads();
  if (d == 0) part[n] = p4[0] + p4[1] + p4[2] + p4[3];
}

// ---------------- single-block: commit reduce + newcount + nsum + prefix ----
__global__ __launch_bounds__(256) void mid_k(
    const double* __restrict__ part, float* __restrict__ out_com,
    const int* __restrict__ hist, const float* __restrict__ ec,
    float* __restrict__ out_cnt, double* __restrict__ nsum,
    int* __restrict__ offs, int* __restrict__ cursor) {
#pragma clang fp contract(off)
  const int t = threadIdx.x;
  __shared__ double dtmp[4];
  __shared__ int itmp[256];

  double s = 0.0;
  for (int i = t; i < kN; i += 256) s += part[i];
#pragma unroll
  for (int m = 32; m; m >>= 1) s += __shfl_xor(s, m);
  if ((t & 63) == 0) dtmp[t >> 6] = s;
  __syncthreads();
  if (t == 0)
    out_com[0] = (float)(0.25 * (dtmp[0] + dtmp[1] + dtmp[2] + dtmp[3]) /
                         (double)((size_t)kN * kD));
  __syncthreads();

  const int base = t * 32;
  double ns = 0.0;
  int run = 0;
  for (int c = 0; c < 32; ++c) {
    const int k = base + c;
    const float nc = 0.99f * ec[k] + 0.01f * (float)hist[k];
    out_cnt[k] = nc;
    ns += (double)nc;
    run += hist[k];
  }
  itmp[t] = run;
  __syncthreads();
  for (int off = 1; off < 256; off <<= 1) {
    const int add = (t >= off) ? itmp[t - off] : 0;
    __syncthreads();
    itmp[t] += add;
    __syncthreads();
  }
  int run2 = itmp[t] - run;
  for (int c = 0; c < 32; ++c) {
    const int k = base + c;
    offs[k] = run2;
    cursor[k] = run2;
    run2 += hist[k];
  }
#pragma unroll
  for (int m = 32; m; m >>= 1) ns += __shfl_xor(ns, m);
  if ((t & 63) == 0) dtmp[t >> 6] = ns;
  __syncthreads();
  if (t == 0) *nsum = dtmp[0] + dtmp[1] + dtmp[2] + dtmp[3];
}

// ---------------- scatter rows into per-code lists ----------------
__global__ __launch_bounds__(256) void scatter_k(const int* __restrict__ idxg,
                                                 int* __restrict__ cursor,
                                                 int* __restrict__ rowlist) {
  const int r = blockIdx.x * 256 + threadIdx.x;
  const int k = idxg[r];
  const int pos = atomicAdd(&cursor[k], 1);
  rowlist[pos] = r;
}

// ---------------- new_avg + new_embed via gathered row sums ----------------
__global__ __launch_bounds__(256) void newavg_k(
    const float* __restrict__ z, const float* __restrict__ ea,
    const int* __restrict__ hist, const int* __restrict__ offs,
    const int* __restrict__ rowlist, const float* __restrict__ out_cnt,
    const double* __restrict__ nsum, float* __restrict__ out_emb,
    float* __restrict__ out_avg) {
#pragma clang fp contract(off)
  const int k = blockIdx.x;
  const int d = threadIdx.x;
  const int c = hist[k];
  const int off = offs[k];
  float s = 0.f;
  for (int j = 0; j < c; ++j)
    s += z[(size_t)rowlist[off + j] * kD + d];
  const size_t o = (size_t)k * kD + d;
  const float na = 0.99f * ea[o] + 0.01f * s;
  out_avg[o] = na;
  const float nf = (float)(*nsum);
  const float nc = out_cnt[k];
  const float keps = 0.08192f;  // fl(K * EPS)
  const float cs = (nc + 1e-5f) / (nf + keps) * nf;
  out_emb[o] = na / cs;
}

extern "C" void kernel_launch(void* const* d_in, const int* in_sizes, int n_in,
                              void* d_out, int out_size, void* d_ws, size_t ws_size,
                              hipStream_t stream) {
  const float* z_e       = (const float*)d_in[0];
  const float* embedding = (const float*)d_in[1];
  const float* ema_count = (const float*)d_in[2];
  const float* ema_avg   = (const float*)d_in[3];

  char* ws = (char*)d_ws;
  int*    hist   = (int*)(ws + OFF_HIST);
  double* nsum   = (double*)(ws + OFF_NS);
  unsigned* segcnt = (unsigned*)(ws + OFF_SEG);
  unsigned long long* rkey = (unsigned long long*)(ws + OFF_RKEY);
  unsigned* rmin = (unsigned*)(ws + OFF_RMIN);
  float*  sz     = (float*)(ws + OFF_SZ);
  float*  cw     = (float*)(ws + OFF_CW);
  _Float16* z16  = (_Float16*)(ws + OFF_Z16);
  _Float16* w16  = (_Float16*)(ws + OFF_W16);
  int2*   flat   = (int2*)(ws + OFF_FLAT);
  int*    idxg   = (int*)(ws + OFF_IDX);
  int*    offs   = (int*)(ws + OFF_OFFS);
  int*    cursor = (int*)(ws + OFF_CUR);
  int*    rowlist= (int*)(ws + OFF_ROWL);
  double* part   = (double*)(ws + OFF_PART);

  float* out_zq  = (float*)d_out;
  float* out_com = out_zq + (size_t)kN * kD;
  float* out_idx = out_com + 1;
  float* out_emb = out_idx + kN;
  float* out_cnt = out_emb + (size_t)kK * kD;
  float* out_avg = out_cnt + kK;

  hipMemsetAsync(ws, 0, ZERO_BYTES, stream);
  hipMemsetAsync(ws + OFF_RKEY, 0xFF, FF_BYTES, stream);

  prep2<<<kN / 256 + kK / 256, 256, 0, stream>>>(z_e, embedding, z16, w16, sz,
                                                 cw);
  score_pass<false><<<(kN / 128) * (kK / 128), 256, 0, stream>>>(
      z16, w16, cw, rmin, nullptr, nullptr);
  score_pass<true><<<(kN / 128) * (kK / 128), 256, 0, stream>>>(
      z16, w16, cw, rmin, segcnt, flat);
  exact_kernel<<<(NSEG * SEGCAP) / 256, 256, 0, stream>>>(
      z_e, embedding, sz, cw, flat, segcnt, rkey);
  finalize_zq<<<kN, 256, 0, stream>>>(rkey, z_e, embedding, idxg, out_idx,
                                      hist, out_zq, part);
  mid_k<<<1, 256, 0, stream>>>(part, out_com, hist, ema_count, out_cnt, nsum,
                               offs, cursor);
  scatter_k<<<kN / 256, 256, 0, stream>>>(idxg, cursor, rowlist);
  newavg_k<<<kK, 256, 0, stream>>>(z_e, ema_avg, hist, offs, rowlist, out_cnt,
                                   nsum, out_emb, out_avg);
}